// Round 7
// baseline (1778.304 us; speedup 1.0000x reference)
//
#include <hip/hip_runtime.h>
#include <stdint.h>

#define D_MODEL 1024
#define RANK    128
#define NH      16
#define DH      64
#define LSEQ    2048
#define NROWS   4096   // B*L
#define BHN     32     // B*NH
#define TOPK    64
#define AROWS   16     // q rows per attention block

// monotonic uint transform: order(f32) == order(uint32)
__device__ __forceinline__ uint32_t fmono(float f) {
    uint32_t ub = (uint32_t)__float_as_int(f);
    uint32_t mask = (uint32_t)((int32_t)ub >> 31) | 0x80000000u;
    return ub ^ mask;
}
__device__ __forceinline__ float imono(uint32_t u) {
    uint32_t mask = (u & 0x80000000u) ? 0x80000000u : 0xFFFFFFFFu;
    return __int_as_float((int32_t)(u ^ mask));
}

// ---------------- stage 1: t[4096,128] = x[4096,1024] @ U[1024,128]
// (UNCHANGED from round-5 passing kernel — projection arithmetic frozen)
__global__ __launch_bounds__(256) void s1_kernel(
    const float* __restrict__ x0, const float* __restrict__ x1, const float* __restrict__ x2,
    const float* __restrict__ U0, const float* __restrict__ U1, const float* __restrict__ U2,
    float* __restrict__ t0, float* __restrict__ t1, float* __restrict__ t2)
{
    const float* x; const float* U; float* t;
    switch (blockIdx.y) {
      case 0: x = x0; U = U0; t = t0; break;
      case 1: x = x1; U = U1; t = t1; break;
      default: x = x2; U = U2; t = t2; break;
    }
    __shared__ float xs[32][36];
    __shared__ float us[32][132];
    const int tid  = threadIdx.x;
    const int row0 = blockIdx.x * 32;
    const int tr4  = (tid >> 5) << 2;   // row group *4
    const int tc4  = (tid & 31) << 2;   // col group *4
    float acc[4][4] = {{0.f}};
    for (int k0 = 0; k0 < D_MODEL; k0 += 32) {
        { int r = tid >> 3, kk = (tid & 7) << 2;
          float4 v = *(const float4*)(x + (size_t)(row0 + r) * D_MODEL + k0 + kk);
          *(float4*)&xs[r][kk] = v; }
        { int kk = tid >> 3, c = (tid & 7) << 4;
          #pragma unroll
          for (int j = 0; j < 4; ++j) {
            float4 v = *(const float4*)(U + (size_t)(k0 + kk) * RANK + c + 4*j);
            *(float4*)&us[kk][c + 4*j] = v; } }
        __syncthreads();
        #pragma unroll
        for (int kk = 0; kk < 32; ++kk) {
            const float a0 = xs[tr4+0][kk];
            const float a1 = xs[tr4+1][kk];
            const float a2 = xs[tr4+2][kk];
            const float a3 = xs[tr4+3][kk];
            const float4 b = *(const float4*)&us[kk][tc4];
            acc[0][0] = fmaf(a0,b.x,acc[0][0]); acc[0][1] = fmaf(a0,b.y,acc[0][1]);
            acc[0][2] = fmaf(a0,b.z,acc[0][2]); acc[0][3] = fmaf(a0,b.w,acc[0][3]);
            acc[1][0] = fmaf(a1,b.x,acc[1][0]); acc[1][1] = fmaf(a1,b.y,acc[1][1]);
            acc[1][2] = fmaf(a1,b.z,acc[1][2]); acc[1][3] = fmaf(a1,b.w,acc[1][3]);
            acc[2][0] = fmaf(a2,b.x,acc[2][0]); acc[2][1] = fmaf(a2,b.y,acc[2][1]);
            acc[2][2] = fmaf(a2,b.z,acc[2][2]); acc[2][3] = fmaf(a2,b.w,acc[2][3]);
            acc[3][0] = fmaf(a3,b.x,acc[3][0]); acc[3][1] = fmaf(a3,b.y,acc[3][1]);
            acc[3][2] = fmaf(a3,b.z,acc[3][2]); acc[3][3] = fmaf(a3,b.w,acc[3][3]);
        }
        __syncthreads();
    }
    #pragma unroll
    for (int i = 0; i < 4; ++i) {
        float4 o = make_float4(acc[i][0], acc[i][1], acc[i][2], acc[i][3]);
        *(float4*)(t + (size_t)(row0 + tr4 + i) * RANK + tc4) = o;
    }
}

// ---------------- stage 2: y[4096,1024] = t[4096,128] @ V^T + b  (UNCHANGED)
__global__ __launch_bounds__(256) void s2_kernel(
    const float* __restrict__ ta, const float* __restrict__ tb, const float* __restrict__ tcc,
    const float* __restrict__ Va, const float* __restrict__ Vb, const float* __restrict__ Vc,
    const float* __restrict__ ba, const float* __restrict__ bb, const float* __restrict__ bc,
    float* __restrict__ oa, float* __restrict__ ob, float* __restrict__ oc,
    float sa, float sb, float scc, int heads)
{
    const float* t; const float* V; const float* bias; float* out; float scale;
    switch (blockIdx.z) {
      case 0: t = ta; V = Va; bias = ba; out = oa; scale = sa; break;
      case 1: t = tb; V = Vb; bias = bb; out = ob; scale = sb; break;
      default: t = tcc; V = Vc; bias = bc; out = oc; scale = scc; break;
    }
    __shared__ float ts[32][68];
    __shared__ float vt[64][132];
    const int tid  = threadIdx.x;
    const int row0 = blockIdx.x * 32;
    const int c0   = blockIdx.y * 128;
    const int tr4  = (tid >> 5) << 2;
    const int tc4  = (tid & 31) << 2;
    float acc[4][4] = {{0.f}};
    for (int k0 = 0; k0 < RANK; k0 += 64) {
        { int r = tid >> 3, kb = (tid & 7) << 3;
          float4 v0 = *(const float4*)(t + (size_t)(row0 + r) * RANK + k0 + kb);
          float4 v1 = *(const float4*)(t + (size_t)(row0 + r) * RANK + k0 + kb + 4);
          *(float4*)&ts[r][kb] = v0; *(float4*)&ts[r][kb+4] = v1; }
        { int ci = tid >> 1, kb = (tid & 1) << 5;
          #pragma unroll
          for (int j = 0; j < 8; ++j) {
            float4 v = *(const float4*)(V + (size_t)(c0 + ci) * RANK + k0 + kb + 4*j);
            vt[kb + 4*j + 0][ci] = v.x; vt[kb + 4*j + 1][ci] = v.y;
            vt[kb + 4*j + 2][ci] = v.z; vt[kb + 4*j + 3][ci] = v.w; } }
        __syncthreads();
        #pragma unroll
        for (int kk = 0; kk < 64; ++kk) {
            const float a0 = ts[tr4+0][kk];
            const float a1 = ts[tr4+1][kk];
            const float a2 = ts[tr4+2][kk];
            const float a3 = ts[tr4+3][kk];
            const float4 b = *(const float4*)&vt[kk][tc4];
            acc[0][0] = fmaf(a0,b.x,acc[0][0]); acc[0][1] = fmaf(a0,b.y,acc[0][1]);
            acc[0][2] = fmaf(a0,b.z,acc[0][2]); acc[0][3] = fmaf(a0,b.w,acc[0][3]);
            acc[1][0] = fmaf(a1,b.x,acc[1][0]); acc[1][1] = fmaf(a1,b.y,acc[1][1]);
            acc[1][2] = fmaf(a1,b.z,acc[1][2]); acc[1][3] = fmaf(a1,b.w,acc[1][3]);
            acc[2][0] = fmaf(a2,b.x,acc[2][0]); acc[2][1] = fmaf(a2,b.y,acc[2][1]);
            acc[2][2] = fmaf(a2,b.z,acc[2][2]); acc[2][3] = fmaf(a2,b.w,acc[2][3]);
            acc[3][0] = fmaf(a3,b.x,acc[3][0]); acc[3][1] = fmaf(a3,b.y,acc[3][1]);
            acc[3][2] = fmaf(a3,b.z,acc[3][2]); acc[3][3] = fmaf(a3,b.w,acc[3][3]);
        }
        __syncthreads();
    }
    #pragma unroll
    for (int i = 0; i < 4; ++i) {
        const int row = row0 + tr4 + i;
        const int c   = c0 + tc4;
        const float4 bv = *(const float4*)(bias + c);
        float4 o;
        o.x = (acc[i][0] + bv.x) * scale;
        o.y = (acc[i][1] + bv.y) * scale;
        o.z = (acc[i][2] + bv.z) * scale;
        o.w = (acc[i][3] + bv.w) * scale;
        if (heads) {
            const int b = row >> 11, tp = row & 2047;
            const int h = c >> 6, dd = c & 63;
            *(float4*)(out + (((size_t)b*NH + h)*LSEQ + tp)*DH + dd) = o;
        } else {
            *(float4*)(out + (size_t)row * D_MODEL + c) = o;
        }
    }
}

// ---------------- attention: per (b,h), 16 q-rows per block; exact top-64 + softmax + PV
// ROUND 6 change: phase-1 lane remap for 16-way LDS broadcast on K reads
//   (r = lane&15 so the 16 lanes of an sg-group read the SAME khs row), plus
//   XOR swizzle of sc storage (s ^ ((r&7)<<2)) to kill the 16-way score-write
//   conflict. Per-dot FMA order is bit-identical to the passing round-5 kernel.
// dynamic LDS layout (floats): unchanged
#define ATTN_SMEM_FLOATS (16*2048 + 64*68 + 16*68)
__global__ __launch_bounds__(512) void attn_kernel(
    const float* __restrict__ qh, const float* __restrict__ kh,
    const float* __restrict__ vh, float* __restrict__ ao)
{
    extern __shared__ float smem[];
    float*    sc   = smem;
    float*    khs  = smem + 16*2048;
    float*    qs   = khs + 64*68;
    unsigned* tiecnt = (unsigned*)qs;
    unsigned* tiebuf = (unsigned*)qs + 16;       // [16][32]
    float*    selp = khs;                        // [16][64]
    unsigned* seli = (unsigned*)(khs + 16*64);   // [16][64]

    const int tid  = threadIdx.x;
    const int lane = tid & 63;
    const int w    = tid >> 6;
    const int bh   = blockIdx.y;
    const int l0   = blockIdx.x * AROWS;
    const float* khb = kh + (size_t)bh * LSEQ * DH;
    const float* vhb = vh + (size_t)bh * LSEQ * DH;

    // phase 0: stage q rows into LDS
    { int sr = tid >> 5, d = (tid & 31) << 1;
      float2 v = *(const float2*)(qh + ((size_t)bh * LSEQ + l0 + sr) * DH + d);
      qs[sr*68 + d] = v.x; qs[sr*68 + d + 1] = v.y; }
    __syncthreads();

    // phase-1 lane mapping: r = lane&15 (16-way broadcast on K), sg = lane>>4
    const int r   = lane & 15;               // row 0..15
    const int sg  = lane >> 4;               // 0..3
    const int sl0 = w*8 + sg*2;              // s_local (even); lane does sl0, sl0+1
    const int xr  = (r & 7) << 2;            // sc storage swizzle (bits 2..4)
    float qr[64];
    #pragma unroll
    for (int d = 0; d < 64; d += 4) {
        const float4 v = *(const float4*)&qs[r*68 + d];
        qr[d] = v.x; qr[d+1] = v.y; qr[d+2] = v.z; qr[d+3] = v.w;
    }
    __syncthreads();

    // phase 1: scores for 16 rows x 2048 s, K staged in 64-s tiles
    for (int t = 0; t < 32; ++t) {
        { int s = tid >> 3, doff = (tid & 7) << 3;
          float4 v0 = *(const float4*)(khb + (size_t)(t*64 + s) * DH + doff);
          float4 v1 = *(const float4*)(khb + (size_t)(t*64 + s) * DH + doff + 4);
          *(float4*)&khs[s*68 + doff]     = v0;
          *(float4*)&khs[s*68 + doff + 4] = v1; }
        __syncthreads();
        const float* k0p = &khs[(size_t)sl0 * 68];
        const float* k1p = &khs[(size_t)(sl0 + 1) * 68];
        float a0 = 0.f, a1 = 0.f;
        #pragma unroll
        for (int d = 0; d < 64; d += 4) {
            const float4 k0v = *(const float4*)&k0p[d];
            const float4 k1v = *(const float4*)&k1p[d];
            a0 = fmaf(qr[d+0], k0v.x, a0); a0 = fmaf(qr[d+1], k0v.y, a0);
            a0 = fmaf(qr[d+2], k0v.z, a0); a0 = fmaf(qr[d+3], k0v.w, a0);
            a1 = fmaf(qr[d+0], k1v.x, a1); a1 = fmaf(qr[d+1], k1v.y, a1);
            a1 = fmaf(qr[d+2], k1v.z, a1); a1 = fmaf(qr[d+3], k1v.w, a1);
        }
        const int s0 = t*64 + sl0;           // even; swizzle keeps bit0 → s0^xr even
        float2 o2; o2.x = a0; o2.y = a1;
        *(float2*)&sc[r*2048 + (s0 ^ xr)] = o2;
        __syncthreads();
    }

    // phases 2/3: per wave, 2 rows: exact top-64 -> softmax -> PV
    const uint64_t lmask_lt = (1ull << lane) - 1ull;
    for (int rr = 0; rr < 2; ++rr) {
        const int row = w*2 + rr;
        const int xr2 = (row & 7) << 2;
        uint32_t u[32];
        #pragma unroll
        for (int c = 0; c < 8; ++c) {
            // logical s = c*256 + lane*4 + m stored at (s ^ xr2); m-bits untouched
            const float4 v = *(const float4*)&sc[row*2048 + c*256 + ((lane << 2) ^ xr2)];
            u[c*4+0] = fmono(v.x); u[c*4+1] = fmono(v.y);
            u[c*4+2] = fmono(v.z); u[c*4+3] = fmono(v.w);
        }
        uint32_t mx = 0u;
        #pragma unroll
        for (int j = 0; j < 32; ++j) mx = mx > u[j] ? mx : u[j];
        #pragma unroll
        for (int off = 32; off; off >>= 1) {
            uint32_t o = (uint32_t)__shfl_xor((int)mx, off, 64);
            mx = mx > o ? mx : o;
        }
        auto cntf = [&u](uint32_t T_) -> int {
            int cc = 0;
            #pragma unroll
            for (int j = 0; j < 32; ++j) cc += (int)__popcll(__ballot(u[j] >= T_));
            return cc;
        };
        // find lower bound with count >= 64, then bisect on mono-uint
        uint32_t lo = 0u;
        const uint32_t hi0 = mx + 1u;
        for (uint32_t step = 1u << 23; ; step <<= 1) {
            uint32_t cand = (mx > step) ? (mx - step) : 0u;
            if (cand == 0u) { lo = 0u; break; }
            if (cntf(cand) >= TOPK) { lo = cand; break; }
            if (step >= 0x40000000u) { lo = 0u; break; }
        }
        uint32_t hi = hi0;
        while (hi - lo > 1u) {
            const uint32_t mid = lo + ((hi - lo) >> 1);
            if (cntf(mid) >= TOPK) lo = mid; else hi = mid;
        }
        const uint32_t T = lo;
        const int cgt  = cntf(T + 1u);   // strictly greater
        const int need = TOPK - cgt;     // ties to take, lowest index first
        if (lane == 0) tiecnt[row] = 0u;
        #pragma unroll
        for (int j = 0; j < 32; ++j) {
            if (u[j] == T) {
                const unsigned sgl = (unsigned)(((j >> 2) << 8) + (lane << 2) + (j & 3));
                unsigned pos = atomicAdd(&tiecnt[row], 1u);
                if (pos < 32u) tiebuf[row*32 + pos] = sgl;
            }
        }
        const unsigned nt = tiecnt[row] < 32u ? tiecnt[row] : 32u;

        // softmax over selected + compaction
        const float mf = imono(mx);
        float zpart = 0.f;
        int base = 0;
        #pragma unroll
        for (int j = 0; j < 32; ++j) {
            const int sgl = ((j >> 2) << 8) + (lane << 2) + (j & 3);
            bool sel = false;
            if (u[j] > T) sel = true;
            else if (u[j] == T) {
                int rank = 0;
                for (unsigned q2 = 0; q2 < nt; ++q2)
                    rank += (tiebuf[row*32 + q2] < (unsigned)sgl) ? 1 : 0;
                sel = (rank < need);
            }
            const uint64_t mk = __ballot(sel);
            float p = 0.f;
            if (sel) {
                p = __expf(imono(u[j]) - mf);
                const int pos = base + (int)__popcll(mk & lmask_lt);
                selp[row*64 + pos] = p;
                seli[row*64 + pos] = (unsigned)sgl;
            }
            zpart += p;
            base  += (int)__popcll(mk);
        }
        #pragma unroll
        for (int off = 32; off; off >>= 1)
            zpart += __shfl_xor(zpart, off, 64);
        const float zinv = 1.0f / zpart;

        // PV: out[row][lane] = sum_j p_j * vh[idx_j][lane]
        float oacc = 0.f;
        #pragma unroll 8
        for (int j = 0; j < TOPK; ++j) {
            const float    p = selp[row*64 + j];
            const unsigned s = seli[row*64 + j];
            oacc = fmaf(p, vhb[(size_t)s * DH + lane], oacc);
        }
        ao[((size_t)(bh >> 4) * LSEQ + l0 + row) * D_MODEL + (bh & 15) * DH + lane] = oacc * zinv;
    }
}

extern "C" void kernel_launch(void* const* d_in, const int* in_sizes, int n_in,
                              void* d_out, int out_size, void* d_ws, size_t ws_size,
                              hipStream_t stream)
{
    const float* q  = (const float*)d_in[0];
    const float* k  = (const float*)d_in[1];
    const float* v  = (const float*)d_in[2];
    const float* Uq = (const float*)d_in[3];
    const float* Vq = (const float*)d_in[4];
    const float* bq = (const float*)d_in[5];
    const float* Uk = (const float*)d_in[6];
    const float* Vk = (const float*)d_in[7];
    const float* bk = (const float*)d_in[8];
    const float* Uv = (const float*)d_in[9];
    const float* Vv = (const float*)d_in[10];
    const float* bv = (const float*)d_in[11];
    const float* Uo = (const float*)d_in[12];
    const float* Vo = (const float*)d_in[13];
    const float* bo = (const float*)d_in[14];
    float* out = (float*)d_out;
    float* ws  = (float*)d_ws;

    float* qh = ws;                       // [32,2048,64]
    float* kh = ws + 4194304;
    float* vh = ws + 8388608;
    float* ao = ws + 12582912;            // [4096,1024]
    float* tq = ws + 16777216;            // [4096,128]
    float* tk = tq + 524288;
    float* tv = tk + 524288;
    float* to = tq;                       // reuse (tq dead after s2 q/k/v)

    // q/k/v projections
    s1_kernel<<<dim3(NROWS/32, 3), 256, 0, stream>>>(q, k, v, Uq, Uk, Uv, tq, tk, tv);
    s2_kernel<<<dim3(NROWS/32, 8, 3), 256, 0, stream>>>(tq, tk, tv, Vq, Vk, Vv, bq, bk, bv,
                                                        qh, kh, vh, 0.125f, 1.f, 1.f, 1);
    // attention
    hipFuncSetAttribute((const void*)attn_kernel,
                        hipFuncAttributeMaxDynamicSharedMemorySize,
                        ATTN_SMEM_FLOATS * 4);
    attn_kernel<<<dim3(LSEQ/AROWS, BHN), 512, ATTN_SMEM_FLOATS * 4, stream>>>(qh, kh, vh, ao);
    // output projection (flat)
    s1_kernel<<<dim3(NROWS/32, 1), 256, 0, stream>>>(ao, ao, ao, Uo, Uo, Uo, to, to, to);
    s2_kernel<<<dim3(NROWS/32, 8, 1), 256, 0, stream>>>(to, to, to, Vo, Vo, Vo, bo, bo, bo,
                                                        out, out, out, 1.f, 1.f, 1.f, 0);
}

// Round 9
// 1304.512 us; speedup vs baseline: 1.3632x; 1.3632x over previous
//
#include <hip/hip_runtime.h>
#include <stdint.h>

#define D_MODEL 1024
#define RANK    128
#define NH      16
#define DH      64
#define LSEQ    2048
#define NROWS   4096   // B*L
#define BHN     32     // B*NH
#define TOPK    64
#define AROWS   16     // q rows per attention block

// monotonic uint transform: order(f32) == order(uint32)
__device__ __forceinline__ uint32_t fmono(float f) {
    uint32_t ub = (uint32_t)__float_as_int(f);
    uint32_t mask = (uint32_t)((int32_t)ub >> 31) | 0x80000000u;
    return ub ^ mask;
}
__device__ __forceinline__ float imono(uint32_t u) {
    uint32_t mask = (u & 0x80000000u) ? 0x80000000u : 0xFFFFFFFFu;
    return __int_as_float((int32_t)(u ^ mask));
}

// ---------------- stage 1: t[4096,128] = x[4096,1024] @ U[1024,128]  (FROZEN)
__global__ __launch_bounds__(256) void s1_kernel(
    const float* __restrict__ x0, const float* __restrict__ x1, const float* __restrict__ x2,
    const float* __restrict__ U0, const float* __restrict__ U1, const float* __restrict__ U2,
    float* __restrict__ t0, float* __restrict__ t1, float* __restrict__ t2)
{
    const float* x; const float* U; float* t;
    switch (blockIdx.y) {
      case 0: x = x0; U = U0; t = t0; break;
      case 1: x = x1; U = U1; t = t1; break;
      default: x = x2; U = U2; t = t2; break;
    }
    __shared__ float xs[32][36];
    __shared__ float us[32][132];
    const int tid  = threadIdx.x;
    const int row0 = blockIdx.x * 32;
    const int tr4  = (tid >> 5) << 2;   // row group *4
    const int tc4  = (tid & 31) << 2;   // col group *4
    float acc[4][4] = {{0.f}};
    for (int k0 = 0; k0 < D_MODEL; k0 += 32) {
        { int r = tid >> 3, kk = (tid & 7) << 2;
          float4 v = *(const float4*)(x + (size_t)(row0 + r) * D_MODEL + k0 + kk);
          *(float4*)&xs[r][kk] = v; }
        { int kk = tid >> 3, c = (tid & 7) << 4;
          #pragma unroll
          for (int j = 0; j < 4; ++j) {
            float4 v = *(const float4*)(U + (size_t)(k0 + kk) * RANK + c + 4*j);
            *(float4*)&us[kk][c + 4*j] = v; } }
        __syncthreads();
        #pragma unroll
        for (int kk = 0; kk < 32; ++kk) {
            const float a0 = xs[tr4+0][kk];
            const float a1 = xs[tr4+1][kk];
            const float a2 = xs[tr4+2][kk];
            const float a3 = xs[tr4+3][kk];
            const float4 b = *(const float4*)&us[kk][tc4];
            acc[0][0] = fmaf(a0,b.x,acc[0][0]); acc[0][1] = fmaf(a0,b.y,acc[0][1]);
            acc[0][2] = fmaf(a0,b.z,acc[0][2]); acc[0][3] = fmaf(a0,b.w,acc[0][3]);
            acc[1][0] = fmaf(a1,b.x,acc[1][0]); acc[1][1] = fmaf(a1,b.y,acc[1][1]);
            acc[1][2] = fmaf(a1,b.z,acc[1][2]); acc[1][3] = fmaf(a1,b.w,acc[1][3]);
            acc[2][0] = fmaf(a2,b.x,acc[2][0]); acc[2][1] = fmaf(a2,b.y,acc[2][1]);
            acc[2][2] = fmaf(a2,b.z,acc[2][2]); acc[2][3] = fmaf(a2,b.w,acc[2][3]);
            acc[3][0] = fmaf(a3,b.x,acc[3][0]); acc[3][1] = fmaf(a3,b.y,acc[3][1]);
            acc[3][2] = fmaf(a3,b.z,acc[3][2]); acc[3][3] = fmaf(a3,b.w,acc[3][3]);
        }
        __syncthreads();
    }
    #pragma unroll
    for (int i = 0; i < 4; ++i) {
        float4 o = make_float4(acc[i][0], acc[i][1], acc[i][2], acc[i][3]);
        *(float4*)(t + (size_t)(row0 + tr4 + i) * RANK + tc4) = o;
    }
}

// ---------------- stage 2: y[4096,1024] = t[4096,128] @ V^T + b  (FROZEN)
__global__ __launch_bounds__(256) void s2_kernel(
    const float* __restrict__ ta, const float* __restrict__ tb, const float* __restrict__ tcc,
    const float* __restrict__ Va, const float* __restrict__ Vb, const float* __restrict__ Vc,
    const float* __restrict__ ba, const float* __restrict__ bb, const float* __restrict__ bc,
    float* __restrict__ oa, float* __restrict__ ob, float* __restrict__ oc,
    float sa, float sb, float scc, int heads)
{
    const float* t; const float* V; const float* bias; float* out; float scale;
    switch (blockIdx.z) {
      case 0: t = ta; V = Va; bias = ba; out = oa; scale = sa; break;
      case 1: t = tb; V = Vb; bias = bb; out = ob; scale = sb; break;
      default: t = tcc; V = Vc; bias = bc; out = oc; scale = scc; break;
    }
    __shared__ float ts[32][68];
    __shared__ float vt[64][132];
    const int tid  = threadIdx.x;
    const int row0 = blockIdx.x * 32;
    const int c0   = blockIdx.y * 128;
    const int tr4  = (tid >> 5) << 2;
    const int tc4  = (tid & 31) << 2;
    float acc[4][4] = {{0.f}};
    for (int k0 = 0; k0 < RANK; k0 += 64) {
        { int r = tid >> 3, kb = (tid & 7) << 3;
          float4 v0 = *(const float4*)(t + (size_t)(row0 + r) * RANK + k0 + kb);
          float4 v1 = *(const float4*)(t + (size_t)(row0 + r) * RANK + k0 + kb + 4);
          *(float4*)&ts[r][kb] = v0; *(float4*)&ts[r][kb+4] = v1; }
        { int ci = tid >> 1, kb = (tid & 1) << 5;
          #pragma unroll
          for (int j = 0; j < 8; ++j) {
            float4 v = *(const float4*)(V + (size_t)(c0 + ci) * RANK + k0 + kb + 4*j);
            vt[kb + 4*j + 0][ci] = v.x; vt[kb + 4*j + 1][ci] = v.y;
            vt[kb + 4*j + 2][ci] = v.z; vt[kb + 4*j + 3][ci] = v.w; } }
        __syncthreads();
        #pragma unroll
        for (int kk = 0; kk < 64; ++kk) {
            const float a0 = ts[tr4+0][kk];
            const float a1 = ts[tr4+1][kk];
            const float a2 = ts[tr4+2][kk];
            const float a3 = ts[tr4+3][kk];
            const float4 b = *(const float4*)&vt[kk][tc4];
            acc[0][0] = fmaf(a0,b.x,acc[0][0]); acc[0][1] = fmaf(a0,b.y,acc[0][1]);
            acc[0][2] = fmaf(a0,b.z,acc[0][2]); acc[0][3] = fmaf(a0,b.w,acc[0][3]);
            acc[1][0] = fmaf(a1,b.x,acc[1][0]); acc[1][1] = fmaf(a1,b.y,acc[1][1]);
            acc[1][2] = fmaf(a1,b.z,acc[1][2]); acc[1][3] = fmaf(a1,b.w,acc[1][3]);
            acc[2][0] = fmaf(a2,b.x,acc[2][0]); acc[2][1] = fmaf(a2,b.y,acc[2][1]);
            acc[2][2] = fmaf(a2,b.z,acc[2][2]); acc[2][3] = fmaf(a2,b.w,acc[2][3]);
            acc[3][0] = fmaf(a3,b.x,acc[3][0]); acc[3][1] = fmaf(a3,b.y,acc[3][1]);
            acc[3][2] = fmaf(a3,b.z,acc[3][2]); acc[3][3] = fmaf(a3,b.w,acc[3][3]);
        }
        __syncthreads();
    }
    #pragma unroll
    for (int i = 0; i < 4; ++i) {
        const int row = row0 + tr4 + i;
        const int c   = c0 + tc4;
        const float4 bv = *(const float4*)(bias + c);
        float4 o;
        o.x = (acc[i][0] + bv.x) * scale;
        o.y = (acc[i][1] + bv.y) * scale;
        o.z = (acc[i][2] + bv.z) * scale;
        o.w = (acc[i][3] + bv.w) * scale;
        if (heads) {
            const int b = row >> 11, tp = row & 2047;
            const int h = c >> 6, dd = c & 63;
            *(float4*)(out + (((size_t)b*NH + h)*LSEQ + tp)*DH + dd) = o;
        } else {
            *(float4*)(out + (size_t)row * D_MODEL + c) = o;
        }
    }
}

// ---------------- attention: per (b,h), 16 q-rows per block
// ROUND 8: revert round-6 remap/swizzle (regressed +25%, conflicts unmoved).
// Back to round-5 memory pattern; schedule change only: 1024 threads (16 waves),
// 4 waves/SIMD instead of 2, to hide barrier/LDS/gather latency.
//   phase 1: each lane computes ONE dot, (r,sl) <-> (w,lane) bijection;
//            FMA chain per (r,s) identical to round-5 -> bit-identical scores.
//   phase 2/3: one row per wave (row = w), body identical to round-5.
// dynamic LDS layout (floats): unchanged from round 5
#define ATTN_SMEM_FLOATS (16*2048 + 64*68 + 16*68)
__global__ __launch_bounds__(1024) void attn_kernel(
    const float* __restrict__ qh, const float* __restrict__ kh,
    const float* __restrict__ vh, float* __restrict__ ao)
{
    extern __shared__ float smem[];
    float*    sc   = smem;
    float*    khs  = smem + 16*2048;
    float*    qs   = khs + 64*68;
    unsigned* tiecnt = (unsigned*)qs;
    unsigned* tiebuf = (unsigned*)qs + 16;       // [16][32]
    float*    selp = khs;                        // [16][64]
    unsigned* seli = (unsigned*)(khs + 16*64);   // [16][64]

    const int tid  = threadIdx.x;
    const int lane = tid & 63;
    const int w    = tid >> 6;                   // 0..15
    const int bh   = blockIdx.y;
    const int l0   = blockIdx.x * AROWS;
    const float* khb = kh + (size_t)bh * LSEQ * DH;
    const float* vhb = vh + (size_t)bh * LSEQ * DH;

    // phase 0: stage q rows into LDS (1024 threads -> 1 float each)
    { int sr = tid >> 6, d = tid & 63;
      qs[sr*68 + d] = qh[((size_t)bh * LSEQ + l0 + sr) * DH + d]; }
    __syncthreads();

    // phase-1 mapping: r = ((w&3)<<2)+(lane>>4) in 0..15, sl = ((w>>2)<<4)+(lane&15) in 0..63
    const int r  = ((w & 3) << 2) + (lane >> 4);
    const int sl = ((w >> 2) << 4) + (lane & 15);
    float qr[64];
    #pragma unroll
    for (int d = 0; d < 64; d += 4) {
        const float4 v = *(const float4*)&qs[r*68 + d];
        qr[d] = v.x; qr[d+1] = v.y; qr[d+2] = v.z; qr[d+3] = v.w;
    }
    __syncthreads();

    // phase 1: scores for 16 rows x 2048 s, K staged in 64-s tiles
    for (int t = 0; t < 32; ++t) {
        { int s = tid >> 4, doff = (tid & 15) << 2;
          float4 v = *(const float4*)(khb + (size_t)(t*64 + s) * DH + doff);
          *(float4*)&khs[s*68 + doff] = v; }
        __syncthreads();
        float a0 = 0.f;
        #pragma unroll
        for (int d = 0; d < 64; d += 4) {
            const float4 k0v = *(const float4*)&khs[sl*68 + d];
            a0 = fmaf(qr[d+0], k0v.x, a0); a0 = fmaf(qr[d+1], k0v.y, a0);
            a0 = fmaf(qr[d+2], k0v.z, a0); a0 = fmaf(qr[d+3], k0v.w, a0);
        }
        sc[r*2048 + t*64 + sl] = a0;
        __syncthreads();
    }

    // phases 2/3: one row per wave: exact top-64 -> softmax -> PV
    const uint64_t lmask_lt = (1ull << lane) - 1ull;
    {
        const int row = w;
        uint32_t u[32];
        #pragma unroll
        for (int c = 0; c < 8; ++c) {
            const float4 v = *(const float4*)&sc[row*2048 + c*256 + lane*4];
            u[c*4+0] = fmono(v.x); u[c*4+1] = fmono(v.y);
            u[c*4+2] = fmono(v.z); u[c*4+3] = fmono(v.w);
        }
        uint32_t mx = 0u;
        #pragma unroll
        for (int j = 0; j < 32; ++j) mx = mx > u[j] ? mx : u[j];
        #pragma unroll
        for (int off = 32; off; off >>= 1) {
            uint32_t o = (uint32_t)__shfl_xor((int)mx, off, 64);
            mx = mx > o ? mx : o;
        }
        auto cntf = [&u](uint32_t T_) -> int {
            int cc = 0;
            #pragma unroll
            for (int j = 0; j < 32; ++j) cc += (int)__popcll(__ballot(u[j] >= T_));
            return cc;
        };
        // find lower bound with count >= 64, then bisect on mono-uint
        uint32_t lo = 0u;
        const uint32_t hi0 = mx + 1u;
        for (uint32_t step = 1u << 23; ; step <<= 1) {
            uint32_t cand = (mx > step) ? (mx - step) : 0u;
            if (cand == 0u) { lo = 0u; break; }
            if (cntf(cand) >= TOPK) { lo = cand; break; }
            if (step >= 0x40000000u) { lo = 0u; break; }
        }
        uint32_t hi = hi0;
        while (hi - lo > 1u) {
            const uint32_t mid = lo + ((hi - lo) >> 1);
            if (cntf(mid) >= TOPK) lo = mid; else hi = mid;
        }
        const uint32_t T = lo;
        const int cgt  = cntf(T + 1u);   // strictly greater
        const int need = TOPK - cgt;     // ties to take, lowest index first
        if (lane == 0) tiecnt[row] = 0u;
        #pragma unroll
        for (int j = 0; j < 32; ++j) {
            if (u[j] == T) {
                const unsigned sgl = (unsigned)(((j >> 2) << 8) + (lane << 2) + (j & 3));
                unsigned pos = atomicAdd(&tiecnt[row], 1u);
                if (pos < 32u) tiebuf[row*32 + pos] = sgl;
            }
        }
        const unsigned nt = tiecnt[row] < 32u ? tiecnt[row] : 32u;

        // softmax over selected + compaction
        const float mf = imono(mx);
        float zpart = 0.f;
        int base = 0;
        #pragma unroll
        for (int j = 0; j < 32; ++j) {
            const int sgl = ((j >> 2) << 8) + (lane << 2) + (j & 3);
            bool sel = false;
            if (u[j] > T) sel = true;
            else if (u[j] == T) {
                int rank = 0;
                for (unsigned q2 = 0; q2 < nt; ++q2)
                    rank += (tiebuf[row*32 + q2] < (unsigned)sgl) ? 1 : 0;
                sel = (rank < need);
            }
            const uint64_t mk = __ballot(sel);
            float p = 0.f;
            if (sel) {
                p = __expf(imono(u[j]) - mf);
                const int pos = base + (int)__popcll(mk & lmask_lt);
                selp[row*64 + pos] = p;
                seli[row*64 + pos] = (unsigned)sgl;
            }
            zpart += p;
            base  += (int)__popcll(mk);
        }
        #pragma unroll
        for (int off = 32; off; off >>= 1)
            zpart += __shfl_xor(zpart, off, 64);
        const float zinv = 1.0f / zpart;

        // PV: out[row][lane] = sum_j p_j * vh[idx_j][lane]
        float oacc = 0.f;
        #pragma unroll 8
        for (int j = 0; j < TOPK; ++j) {
            const float    p = selp[row*64 + j];
            const unsigned s = seli[row*64 + j];
            oacc = fmaf(p, vhb[(size_t)s * DH + lane], oacc);
        }
        ao[((size_t)(bh >> 4) * LSEQ + l0 + row) * D_MODEL + (bh & 15) * DH + lane] = oacc * zinv;
    }
}

extern "C" void kernel_launch(void* const* d_in, const int* in_sizes, int n_in,
                              void* d_out, int out_size, void* d_ws, size_t ws_size,
                              hipStream_t stream)
{
    const float* q  = (const float*)d_in[0];
    const float* k  = (const float*)d_in[1];
    const float* v  = (const float*)d_in[2];
    const float* Uq = (const float*)d_in[3];
    const float* Vq = (const float*)d_in[4];
    const float* bq = (const float*)d_in[5];
    const float* Uk = (const float*)d_in[6];
    const float* Vk = (const float*)d_in[7];
    const float* bk = (const float*)d_in[8];
    const float* Uv = (const float*)d_in[9];
    const float* Vv = (const float*)d_in[10];
    const float* bv = (const float*)d_in[11];
    const float* Uo = (const float*)d_in[12];
    const float* Vo = (const float*)d_in[13];
    const float* bo = (const float*)d_in[14];
    float* out = (float*)d_out;
    float* ws  = (float*)d_ws;

    float* qh = ws;                       // [32,2048,64]
    float* kh = ws + 4194304;
    float* vh = ws + 8388608;
    float* ao = ws + 12582912;            // [4096,1024]
    float* tq = ws + 16777216;            // [4096,128]
    float* tk = tq + 524288;
    float* tv = tk + 524288;
    float* to = tq;                       // reuse (tq dead after s2 q/k/v)

    // q/k/v projections
    s1_kernel<<<dim3(NROWS/32, 3), 256, 0, stream>>>(q, k, v, Uq, Uk, Uv, tq, tk, tv);
    s2_kernel<<<dim3(NROWS/32, 8, 3), 256, 0, stream>>>(tq, tk, tv, Vq, Vk, Vv, bq, bk, bv,
                                                        qh, kh, vh, 0.125f, 1.f, 1.f, 1);
    // attention
    hipFuncSetAttribute((const void*)attn_kernel,
                        hipFuncAttributeMaxDynamicSharedMemorySize,
                        ATTN_SMEM_FLOATS * 4);
    attn_kernel<<<dim3(LSEQ/AROWS, BHN), 1024, ATTN_SMEM_FLOATS * 4, stream>>>(qh, kh, vh, ao);
    // output projection (flat)
    s1_kernel<<<dim3(NROWS/32, 1), 256, 0, stream>>>(ao, ao, ao, Uo, Uo, Uo, to, to, to);
    s2_kernel<<<dim3(NROWS/32, 8, 1), 256, 0, stream>>>(to, to, to, Vo, Vo, Vo, bo, bo, bo,
                                                        out, out, out, 1.f, 1.f, 1.f, 0);
}